// Round 12
// baseline (287.505 us; speedup 1.0000x reference)
//
#include <hip/hip_runtime.h>
#include <hip/hip_bf16.h>
#include <cstddef>
#include <cstdint>

#define IN_C 256
#define OUT_C 64
#define NEG_SLOPE 0.2f
#define BKT2 256       // nodes per destination bucket (bucket = c >> 8)
#define PCHUNK 4096    // edges per block in partition role
#define MAXB 512       // bucket-slot array size (>= number of buckets = 391)
#define CAP 9728       // fixed record capacity per bucket (mean 8163, +17 sigma)

typedef __attribute__((ext_vector_type(4))) float f32x4;
typedef __attribute__((ext_vector_type(2))) float f32x2;
typedef __attribute__((ext_vector_type(8))) short s16x8;

__device__ __forceinline__ ushort f2bf(float f)
{
    uint32_t u = __float_as_uint(f);
    u += 0x7fffu + ((u >> 16) & 1u);   // round-to-nearest-even
    return (ushort)(u >> 16);
}

// pack two fp32 -> {bf16(f1)<<16 | bf16(f0)}
__device__ __forceinline__ uint32_t pack_bf2(float f0, float f1)
{
    const uint32_t u0 = __float_as_uint(f0) + 0x8000u;
    const uint32_t u1 = __float_as_uint(f1) + 0x8000u;
    return (u1 & 0xffff0000u) | (u0 >> 16);
}

// ---------------------------------------------------------------------------
// W -> bf16 B-fragment order (blocks 0..63); block 64 inits bucket cursors.
// ---------------------------------------------------------------------------
__global__ __launch_bounds__(256) void wconv_kernel(
    const float* __restrict__ W, ushort* __restrict__ wfrag,
    int* __restrict__ cursor, int nb)
{
    if (blockIdx.x == 64) {
        for (int i = threadIdx.x; i < nb; i += 256) cursor[i] = i * CAP;
        return;
    }
    const int idx = blockIdx.x * 256 + threadIdx.x;
    const int j = idx & 7;
    const int l = (idx >> 3) & 63;
    const int n = (idx >> 9) & 3;
    const int t = idx >> 11;
    const int k   = t * 32 + ((l >> 4) << 3) + j;
    const int col = n * 16 + (l & 15);
    wfrag[idx] = f2bf(W[col * IN_C + k]);
}

// ---------------------------------------------------------------------------
// Merged kernel: blocks [0, PB) run the partition role, blocks [PB, PB+MB)
// run the MFMA projection role.  The two roles touch disjoint memory
// (partition: ei -> rec/cursor; mfma: x/wfrag/a -> hb/s_i/s_j), so they
// overlap on the CUs instead of serializing as two dispatches.
// 256 threads, 32 KB LDS union.
// ---------------------------------------------------------------------------
__global__ __launch_bounds__(256) void fused_proj_part(
    const float* __restrict__ x, const ushort* __restrict__ wfrag,
    const float* __restrict__ a, ushort* __restrict__ hb,
    float* __restrict__ s_i, float* __restrict__ s_j, int n_nodes,
    const int* __restrict__ ei, int* __restrict__ cursor,
    uint32_t* __restrict__ rec, int n_edges, int nb, int pb)
{
    __shared__ __align__(16) char smem[32 * 1024];
    __shared__ int wtot[4];

    const int tid = threadIdx.x;

    if ((int)blockIdx.x < pb) {
        // ----- partition role: 4096 edges, LDS counting-sort, coalesced flush
        int* hist  = (int*)smem;                     // 2 KB (512 slots)
        int* lbase = (int*)(smem + 2048);            // 2 KB
        int* gbase = (int*)(smem + 4096);            // 2 KB
        int* lcur  = (int*)(smem + 6144);            // 2 KB
        uint32_t* srt  = (uint32_t*)(smem + 8192);   // 16 KB
        uint16_t* bmap = (uint16_t*)(smem + 24576);  // 8 KB

        const int base = blockIdx.x * PCHUNK;
        const int lim  = min(PCHUNK, n_edges - base);

        hist[tid] = 0;
        hist[tid + 256] = 0;
        __syncthreads();

        int rA[PCHUNK / 256], cA[PCHUNK / 256];
        #pragma unroll
        for (int k = 0; k < PCHUNK / 256; ++k) {
            const int i = tid + (k << 8);
            if (i < lim) {
                rA[k] = __builtin_nontemporal_load(ei + base + i);
                cA[k] = __builtin_nontemporal_load(ei + n_edges + base + i);
                atomicAdd(&hist[(uint32_t)cA[k] >> 8], 1);
            }
        }
        __syncthreads();

        // scan 512 slots with 256 threads: thread t owns slots 2t, 2t+1.
        // Wave-level shfl scan of pair-sums (register-only), then 4 wave
        // totals combined -> 2 barriers total instead of 18.
        const int h0 = hist[2 * tid];
        const int h1 = hist[2 * tid + 1];
        const int pv = h0 + h1;
        const int lane = tid & 63;
        const int w    = tid >> 6;
        int incl = pv;
        #pragma unroll
        for (int d = 1; d < 64; d <<= 1) {
            const int o = __shfl_up(incl, d, 64);
            if (lane >= d) incl += o;
        }
        if (lane == 63) wtot[w] = incl;
        __syncthreads();
        int wpre = 0;
        for (int q = 0; q < w; ++q) wpre += wtot[q];
        const int excl_pair = incl + wpre - pv;   // exclusive prefix of pair tid

        lbase[2 * tid]     = excl_pair;
        lbase[2 * tid + 1] = excl_pair + h0;
        lcur[2 * tid]      = excl_pair;
        lcur[2 * tid + 1]  = excl_pair + h0;
        gbase[2 * tid]     = (2 * tid < nb && h0 > 0)
                             ? atomicAdd(&cursor[2 * tid], h0) : 0;
        gbase[2 * tid + 1] = (2 * tid + 1 < nb && h1 > 0)
                             ? atomicAdd(&cursor[2 * tid + 1], h1) : 0;
        __syncthreads();

        // scatter into LDS staging in block-sorted order
        #pragma unroll
        for (int k = 0; k < PCHUNK / 256; ++k) {
            const int i = tid + (k << 8);
            if (i < lim) {
                const int r = rA[k];
                const int c = cA[k];
                const int b = (uint32_t)c >> 8;
                const int pos = atomicAdd(&lcur[b], 1);
                srt[pos]  = ((uint32_t)r << 8) | (uint32_t)(c & (BKT2 - 1));
                bmap[pos] = (uint16_t)b;
            }
        }
        __syncthreads();

        // linear flush: piecewise-contiguous coalesced burst
        for (int i = tid; i < lim; i += 256) {
            const int b = bmap[i];
            rec[gbase[b] + (i - lbase[b])] = srt[i];
        }
        return;
    }

    // ----- MFMA projection role: h = x @ W^T (bf16), s_i/s_j (fp32)
    ushort* Bs = (ushort*)smem;   // 32 KB

    for (int i = tid; i < 2048; i += 256)
        ((float4*)Bs)[i] = ((const float4*)wfrag)[i];
    __syncthreads();

    const int lane = tid & 63;
    const int wv   = tid >> 6;
    const int m    = lane & 15;
    const int quad = lane >> 4;

    const int base = (blockIdx.x - pb) * 64 + wv * 16;
    int row = base + m;
    if (row >= n_nodes) row = n_nodes - 1;   // clamped loads, masked stores

    f32x4 acc0 = {0.f, 0.f, 0.f, 0.f};
    f32x4 acc1 = {0.f, 0.f, 0.f, 0.f};
    f32x4 acc2 = {0.f, 0.f, 0.f, 0.f};
    f32x4 acc3 = {0.f, 0.f, 0.f, 0.f};

    const float* xrow = x + (size_t)row * IN_C + quad * 8;

    #pragma unroll
    for (int t = 0; t < 8; ++t) {
        const float4 xa = *(const float4*)(xrow + t * 32);
        const float4 xb = *(const float4*)(xrow + t * 32 + 4);
        union { s16x8 v; uint32_t u[4]; } af;
        af.u[0] = pack_bf2(xa.x, xa.y);
        af.u[1] = pack_bf2(xa.z, xa.w);
        af.u[2] = pack_bf2(xb.x, xb.y);
        af.u[3] = pack_bf2(xb.z, xb.w);

        const s16x8 b0 = *(const s16x8*)(Bs + ((t * 4 + 0) * 64 + lane) * 8);
        const s16x8 b1 = *(const s16x8*)(Bs + ((t * 4 + 1) * 64 + lane) * 8);
        const s16x8 b2 = *(const s16x8*)(Bs + ((t * 4 + 2) * 64 + lane) * 8);
        const s16x8 b3 = *(const s16x8*)(Bs + ((t * 4 + 3) * 64 + lane) * 8);

        acc0 = __builtin_amdgcn_mfma_f32_16x16x32_bf16(af.v, b0, acc0, 0, 0, 0);
        acc1 = __builtin_amdgcn_mfma_f32_16x16x32_bf16(af.v, b1, acc1, 0, 0, 0);
        acc2 = __builtin_amdgcn_mfma_f32_16x16x32_bf16(af.v, b2, acc2, 0, 0, 0);
        acc3 = __builtin_amdgcn_mfma_f32_16x16x32_bf16(af.v, b3, acc3, 0, 0, 0);
    }

    // epilogue: C/D layout col = lane&15, row = quad*4 + reg
    const int c0 = lane & 15;
    const float ai0 = a[c0],      ai1 = a[c0 + 16], ai2 = a[c0 + 32], ai3 = a[c0 + 48];
    const float aj0 = a[64 + c0], aj1 = a[80 + c0], aj2 = a[96 + c0], aj3 = a[112 + c0];

    #pragma unroll
    for (int r = 0; r < 4; ++r) {
        const int rowr = base + quad * 4 + r;
        float pi = acc0[r] * ai0 + acc1[r] * ai1 + acc2[r] * ai2 + acc3[r] * ai3;
        float pj = acc0[r] * aj0 + acc1[r] * aj1 + acc2[r] * aj2 + acc3[r] * aj3;
        pi += __shfl_xor(pi, 1, 64);  pj += __shfl_xor(pj, 1, 64);
        pi += __shfl_xor(pi, 2, 64);  pj += __shfl_xor(pj, 2, 64);
        pi += __shfl_xor(pi, 4, 64);  pj += __shfl_xor(pj, 4, 64);
        pi += __shfl_xor(pi, 8, 64);  pj += __shfl_xor(pj, 8, 64);
        if (rowr < n_nodes) {
            ushort* hr = hb + (size_t)rowr * OUT_C + c0;
            hr[0]  = f2bf(acc0[r]);
            hr[16] = f2bf(acc1[r]);
            hr[32] = f2bf(acc2[r]);
            hr[48] = f2bf(acc3[r]);
            if (c0 == 0) { s_i[rowr] = pi; s_j[rowr] = pj; }
        }
    }
}

// ---------------------------------------------------------------------------
// Fused sort+gather: one 1024-thread block per 256-node bucket.
// (unchanged from the 280 µs measured version)
// ---------------------------------------------------------------------------
__global__ __launch_bounds__(1024) void sortgather_kernel(
    const uint32_t* __restrict__ rec, const ushort* __restrict__ hb,
    const float* __restrict__ s_i, const float* __restrict__ s_j,
    const int* __restrict__ cursor, float* __restrict__ out, int n_nodes)
{
    __shared__ uint32_t srt[CAP];        // 38 KB sorted records
    __shared__ int hcnt[BKT2];           // 1 KB
    __shared__ int nstart[BKT2 + 1];     // 1 KB
    __shared__ int lcur[BKT2];           // 1 KB
    __shared__ int sscan[BKT2];          // 1 KB

    const int b     = blockIdx.x;
    const int tid   = threadIdx.x;
    const int start = b * CAP;
    const int cnt   = min(cursor[b] - start, CAP);

    if (tid < BKT2) hcnt[tid] = 0;
    __syncthreads();

    // phase 1: histogram (vectorized global read; rec is L2-resident)
    const int cnt4 = cnt >> 2;
    for (int i = tid; i < cnt4; i += 1024) {
        const uint4 rv4 = ((const uint4*)(rec + start))[i];
        atomicAdd(&hcnt[rv4.x & (BKT2 - 1)], 1);
        atomicAdd(&hcnt[rv4.y & (BKT2 - 1)], 1);
        atomicAdd(&hcnt[rv4.z & (BKT2 - 1)], 1);
        atomicAdd(&hcnt[rv4.w & (BKT2 - 1)], 1);
    }
    for (int i = (cnt & ~3) + tid; i < cnt; i += 1024)
        atomicAdd(&hcnt[rec[start + i] & (BKT2 - 1)], 1);
    __syncthreads();

    // phase 2: inclusive scan over 256 node counts
    if (tid < BKT2) sscan[tid] = hcnt[tid];
    __syncthreads();
    for (int off = 1; off < BKT2; off <<= 1) {
        int mine = 0, other = 0;
        if (tid < BKT2) {
            mine  = sscan[tid];
            other = (tid >= off) ? sscan[tid - off] : 0;
        }
        __syncthreads();
        if (tid < BKT2) sscan[tid] = mine + other;
        __syncthreads();
    }
    if (tid < BKT2) {
        const int excl = sscan[tid] - hcnt[tid];
        nstart[tid] = excl;
        lcur[tid]   = excl;
    }
    if (tid == 0) nstart[BKT2] = cnt;
    __syncthreads();

    // phase 3: scatter into per-node CSR order inside LDS
    for (int i = tid; i < cnt; i += 1024) {
        const uint32_t rv = rec[start + i];
        srt[atomicAdd(&lcur[rv & (BKT2 - 1)], 1)] = rv;
    }
    __syncthreads();

    // phase 4: per-node gather (16 nodes per wave, records from LDS)
    const int lane = tid & 63;
    const int wv   = tid >> 6;
    const int g    = lane >> 3;          // edge slot 0..7
    const int l8   = lane & 7;           // channel block
    const uint32_t loff = (uint32_t)(l8 << 4);
    const char* hbB = (const char*)hb;

    for (int k = 0; k < BKT2 / 16; ++k) {
        const int nl   = wv * (BKT2 / 16) + k;
        const int node = b * BKT2 + nl;
        if (node >= n_nodes) break;
        const int o  = nstart[nl];
        const int oe = nstart[nl + 1];
        const float si = s_i[node];

        f32x2 a01 = {0.f, 0.f}, a23 = {0.f, 0.f};
        f32x2 a45 = {0.f, 0.f}, a67 = {0.f, 0.f};
        float dsum = 0.f;

        int e = o;
        for (; e + 32 <= oe; e += 32) {
            uint32_t rv[4];
            #pragma unroll
            for (int q = 0; q < 4; ++q) rv[q] = srt[e + q * 8 + g];
            float sj[4]; uint32_t off[4];
            #pragma unroll
            for (int q = 0; q < 4; ++q) {
                sj[q]  = s_j[rv[q] >> 8];
                off[q] = ((rv[q] & 0xFFFFFF00u) >> 1) + loff;   // r*128 + l8*16
            }
            uint4 hv[4];
            #pragma unroll
            for (int q = 0; q < 4; ++q) hv[q] = *(const uint4*)(hbB + off[q]);
            #pragma unroll
            for (int q = 0; q < 4; ++q) {
                const float t  = si + sj[q];
                const float ex = __expf(fmaxf(t, NEG_SLOPE * t));
                const f32x2 e2 = {ex, ex};
                f32x2 h;
                h[0] = __uint_as_float(hv[q].x << 16);
                h[1] = __uint_as_float(hv[q].x & 0xffff0000u);
                a01 += e2 * h;
                h[0] = __uint_as_float(hv[q].y << 16);
                h[1] = __uint_as_float(hv[q].y & 0xffff0000u);
                a23 += e2 * h;
                h[0] = __uint_as_float(hv[q].z << 16);
                h[1] = __uint_as_float(hv[q].z & 0xffff0000u);
                a45 += e2 * h;
                h[0] = __uint_as_float(hv[q].w << 16);
                h[1] = __uint_as_float(hv[q].w & 0xffff0000u);
                a67 += e2 * h;
                dsum += ex;
            }
        }
        for (; e + 8 <= oe; e += 8) {
            const uint32_t rv = srt[e + g];
            const float sjv = s_j[rv >> 8];
            const uint32_t off = ((rv & 0xFFFFFF00u) >> 1) + loff;
            const uint4 hv = *(const uint4*)(hbB + off);
            const float t  = si + sjv;
            const float ex = __expf(fmaxf(t, NEG_SLOPE * t));
            const f32x2 e2 = {ex, ex};
            f32x2 h;
            h[0] = __uint_as_float(hv.x << 16);
            h[1] = __uint_as_float(hv.x & 0xffff0000u);
            a01 += e2 * h;
            h[0] = __uint_as_float(hv.y << 16);
            h[1] = __uint_as_float(hv.y & 0xffff0000u);
            a23 += e2 * h;
            h[0] = __uint_as_float(hv.z << 16);
            h[1] = __uint_as_float(hv.z & 0xffff0000u);
            a45 += e2 * h;
            h[0] = __uint_as_float(hv.w << 16);
            h[1] = __uint_as_float(hv.w & 0xffff0000u);
            a67 += e2 * h;
            dsum += ex;
        }
        if (e < oe) {
            const int m = oe - e;                    // 1..7
            const uint32_t rv = srt[e + (g < m ? g : m - 1)];
            const float sjv = s_j[rv >> 8];
            const uint32_t off = ((rv & 0xFFFFFF00u) >> 1) + loff;
            const uint4 hv = *(const uint4*)(hbB + off);
            const float t  = si + sjv;
            const float ex = (g < m) ? __expf(fmaxf(t, NEG_SLOPE * t)) : 0.f;
            const f32x2 e2 = {ex, ex};
            f32x2 h;
            h[0] = __uint_as_float(hv.x << 16);
            h[1] = __uint_as_float(hv.x & 0xffff0000u);
            a01 += e2 * h;
            h[0] = __uint_as_float(hv.y << 16);
            h[1] = __uint_as_float(hv.y & 0xffff0000u);
            a23 += e2 * h;
            h[0] = __uint_as_float(hv.z << 16);
            h[1] = __uint_as_float(hv.z & 0xffff0000u);
            a45 += e2 * h;
            h[0] = __uint_as_float(hv.w << 16);
            h[1] = __uint_as_float(hv.w & 0xffff0000u);
            a67 += e2 * h;
            dsum += ex;
        }

        // cross-group reduction over the 8 edge slots (l8 preserved)
        #pragma unroll
        for (int s = 8; s <= 32; s <<= 1) {
            a01[0] += __shfl_xor(a01[0], s, 64);
            a01[1] += __shfl_xor(a01[1], s, 64);
            a23[0] += __shfl_xor(a23[0], s, 64);
            a23[1] += __shfl_xor(a23[1], s, 64);
            a45[0] += __shfl_xor(a45[0], s, 64);
            a45[1] += __shfl_xor(a45[1], s, 64);
            a67[0] += __shfl_xor(a67[0], s, 64);
            a67[1] += __shfl_xor(a67[1], s, 64);
            dsum   += __shfl_xor(dsum,   s, 64);
        }

        // self loop: row = col = node
        const float t0  = si + s_j[node];
        const float ex0 = __expf(fmaxf(t0, NEG_SLOPE * t0));
        const uint4 hs = *(const uint4*)(hbB + (size_t)node * 128 + loff);
        a01[0] += ex0 * __uint_as_float(hs.x << 16);
        a01[1] += ex0 * __uint_as_float(hs.x & 0xffff0000u);
        a23[0] += ex0 * __uint_as_float(hs.y << 16);
        a23[1] += ex0 * __uint_as_float(hs.y & 0xffff0000u);
        a45[0] += ex0 * __uint_as_float(hs.z << 16);
        a45[1] += ex0 * __uint_as_float(hs.z & 0xffff0000u);
        a67[0] += ex0 * __uint_as_float(hs.w << 16);
        a67[1] += ex0 * __uint_as_float(hs.w & 0xffff0000u);
        dsum += ex0;

        if (g == 0) {
            const float inv = 1.0f / dsum;
            f32x4 o4;
            o4[0] = a01[0] * inv;
            o4[1] = a01[1] * inv;
            o4[2] = a23[0] * inv;
            o4[3] = a23[1] * inv;
            float* op = out + (size_t)node * OUT_C + (l8 << 3);
            __builtin_nontemporal_store(o4, (f32x4*)op);
            o4[0] = a45[0] * inv;
            o4[1] = a45[1] * inv;
            o4[2] = a67[0] * inv;
            o4[3] = a67[1] * inv;
            __builtin_nontemporal_store(o4, (f32x4*)(op + 4));
        }
    }
}

extern "C" void kernel_launch(void* const* d_in, const int* in_sizes, int n_in,
                              void* d_out, int out_size, void* d_ws, size_t ws_size,
                              hipStream_t stream)
{
    const float* x  = (const float*)d_in[0];
    const int*   ei = (const int*)d_in[1];
    const float* W  = (const float*)d_in[2];
    const float* a  = (const float*)d_in[3];

    const int N  = in_sizes[0] / IN_C;     // 100000
    const int E  = in_sizes[1] / 2;        // 3200000
    const int NB = (N + BKT2 - 1) / BKT2;  // 391

    float* out = (float*)d_out;

    // workspace carve-up (~29 MB)
    char* ws = (char*)d_ws;
    ushort* hb      = (ushort*)ws;                ws += (size_t)N * OUT_C * 2;  // 12.8 MB
    float*  s_i     = (float*)ws;                 ws += (size_t)N * 4;
    float*  s_j     = (float*)ws;                 ws += (size_t)N * 4;
    int*    cursor  = (int*)ws;                   ws += (size_t)MAXB * 4;
    ws = (char*)(((uintptr_t)ws + 15) & ~(uintptr_t)15);
    ushort* wfrag   = (ushort*)ws;                ws += 32 * 64 * 8 * 2;        // 32 KB
    ws = (char*)(((uintptr_t)ws + 15) & ~(uintptr_t)15);
    uint32_t* rec   = (uint32_t*)ws;              // NB * CAP * 4 B = 15.2 MB

    // 1. W fragment conversion + cursor init
    hipLaunchKernelGGL(wconv_kernel, dim3(65), dim3(256), 0, stream,
                       W, wfrag, cursor, NB);

    // 2. merged projection (MFMA) + partition — independent roles, one dispatch
    const int PB = (E + PCHUNK - 1) / PCHUNK;   // 782 partition blocks (first)
    const int MB = (N + 63) / 64;               // 1563 mfma blocks
    hipLaunchKernelGGL(fused_proj_part, dim3(PB + MB), dim3(256), 0, stream,
                       x, wfrag, a, hb, s_i, s_j, N,
                       ei, cursor, rec, E, NB, PB);

    // 3. fused per-bucket LDS sort + gather-aggregate
    hipLaunchKernelGGL(sortgather_kernel, dim3(NB), dim3(1024), 0, stream,
                       rec, hb, s_i, s_j, cursor, out, N);
}

// Round 14
// 280.071 us; speedup vs baseline: 1.0265x; 1.0265x over previous
//
#include <hip/hip_runtime.h>
#include <hip/hip_bf16.h>
#include <cstddef>
#include <cstdint>

#define IN_C 256
#define OUT_C 64
#define NEG_SLOPE 0.2f
#define BKT2 256       // nodes per destination bucket (bucket = c >> 8)
#define PCHUNK 4096    // edges per block in partition role
#define MAXB 512       // bucket-slot array size (>= number of buckets = 391)
#define CAP 9728       // fixed record capacity per bucket (mean 8163, +17 sigma)

typedef __attribute__((ext_vector_type(4))) float f32x4;
typedef __attribute__((ext_vector_type(2))) float f32x2;
typedef __attribute__((ext_vector_type(8))) short s16x8;

__device__ __forceinline__ ushort f2bf(float f)
{
    uint32_t u = __float_as_uint(f);
    u += 0x7fffu + ((u >> 16) & 1u);   // round-to-nearest-even
    return (ushort)(u >> 16);
}

// pack two fp32 -> {bf16(f1)<<16 | bf16(f0)}
__device__ __forceinline__ uint32_t pack_bf2(float f0, float f1)
{
    const uint32_t u0 = __float_as_uint(f0) + 0x8000u;
    const uint32_t u1 = __float_as_uint(f1) + 0x8000u;
    return (u1 & 0xffff0000u) | (u0 >> 16);
}

// ---------------------------------------------------------------------------
// W -> bf16 B-fragment order (blocks 0..63); block 64 inits bucket cursors.
// ---------------------------------------------------------------------------
__global__ __launch_bounds__(256) void wconv_kernel(
    const float* __restrict__ W, ushort* __restrict__ wfrag,
    int* __restrict__ cursor, int nb)
{
    if (blockIdx.x == 64) {
        for (int i = threadIdx.x; i < nb; i += 256) cursor[i] = i * CAP;
        return;
    }
    const int idx = blockIdx.x * 256 + threadIdx.x;
    const int j = idx & 7;
    const int l = (idx >> 3) & 63;
    const int n = (idx >> 9) & 3;
    const int t = idx >> 11;
    const int k   = t * 32 + ((l >> 4) << 3) + j;
    const int col = n * 16 + (l & 15);
    wfrag[idx] = f2bf(W[col * IN_C + k]);
}

// ---------------------------------------------------------------------------
// Merged kernel, INTERLEAVED roles: bx%3==2 -> partition (pid=bx/3, exactly
// PB blocks), else MFMA projection (mid=bx-bx/3, guard >= mb).  1:2 mix per
// CU so partition's latency stalls are filled by mfma's VALU/MFMA waves.
// LDS exactly 32 KB (wtot aliased into srt region) -> 5 blocks/CU.
// ---------------------------------------------------------------------------
__global__ __launch_bounds__(256) void fused_proj_part(
    const float* __restrict__ x, const ushort* __restrict__ wfrag,
    const float* __restrict__ a, ushort* __restrict__ hb,
    float* __restrict__ s_i, float* __restrict__ s_j, int n_nodes,
    const int* __restrict__ ei, int* __restrict__ cursor,
    uint32_t* __restrict__ rec, int n_edges, int nb, int mb)
{
    __shared__ __align__(16) char smem[32 * 1024];

    const int tid = threadIdx.x;
    const int bx  = (int)blockIdx.x;

    if (bx % 3 == 2) {
        // ----- partition role: 4096 edges, LDS counting-sort, coalesced flush
        const int pid = bx / 3;
        int* hist  = (int*)smem;                     // 2 KB (512 slots)
        int* lbase = (int*)(smem + 2048);            // 2 KB
        int* gbase = (int*)(smem + 4096);            // 2 KB
        int* lcur  = (int*)(smem + 6144);            // 2 KB
        uint32_t* srt  = (uint32_t*)(smem + 8192);   // 16 KB
        uint16_t* bmap = (uint16_t*)(smem + 24576);  // 8 KB
        int* wtot = (int*)(smem + 8192);             // aliases srt[0..3]:
        // written before barrier-1, read right after; srt first written
        // only after barrier-2 -> no overlap.

        const int base = pid * PCHUNK;
        const int lim  = min(PCHUNK, n_edges - base);

        hist[tid] = 0;
        hist[tid + 256] = 0;
        __syncthreads();

        int rA[PCHUNK / 256], cA[PCHUNK / 256];
        #pragma unroll
        for (int k = 0; k < PCHUNK / 256; ++k) {
            const int i = tid + (k << 8);
            if (i < lim) {
                rA[k] = __builtin_nontemporal_load(ei + base + i);
                cA[k] = __builtin_nontemporal_load(ei + n_edges + base + i);
                atomicAdd(&hist[(uint32_t)cA[k] >> 8], 1);
            }
        }
        __syncthreads();

        // scan 512 slots with 256 threads: thread t owns slots 2t, 2t+1.
        const int h0 = hist[2 * tid];
        const int h1 = hist[2 * tid + 1];
        const int pv = h0 + h1;
        const int lane = tid & 63;
        const int w    = tid >> 6;
        int incl = pv;
        #pragma unroll
        for (int d = 1; d < 64; d <<= 1) {
            const int o = __shfl_up(incl, d, 64);
            if (lane >= d) incl += o;
        }
        if (lane == 63) wtot[w] = incl;
        __syncthreads();
        int wpre = 0;
        for (int q = 0; q < w; ++q) wpre += wtot[q];
        const int excl_pair = incl + wpre - pv;   // exclusive prefix of pair tid

        lbase[2 * tid]     = excl_pair;
        lbase[2 * tid + 1] = excl_pair + h0;
        lcur[2 * tid]      = excl_pair;
        lcur[2 * tid + 1]  = excl_pair + h0;
        gbase[2 * tid]     = (2 * tid < nb && h0 > 0)
                             ? atomicAdd(&cursor[2 * tid], h0) : 0;
        gbase[2 * tid + 1] = (2 * tid + 1 < nb && h1 > 0)
                             ? atomicAdd(&cursor[2 * tid + 1], h1) : 0;
        __syncthreads();

        // scatter into LDS staging in block-sorted order
        #pragma unroll
        for (int k = 0; k < PCHUNK / 256; ++k) {
            const int i = tid + (k << 8);
            if (i < lim) {
                const int r = rA[k];
                const int c = cA[k];
                const int b = (uint32_t)c >> 8;
                const int pos = atomicAdd(&lcur[b], 1);
                srt[pos]  = ((uint32_t)r << 8) | (uint32_t)(c & (BKT2 - 1));
                bmap[pos] = (uint16_t)b;
            }
        }
        __syncthreads();

        // linear flush: piecewise-contiguous coalesced burst
        for (int i = tid; i < lim; i += 256) {
            const int b = bmap[i];
            rec[gbase[b] + (i - lbase[b])] = srt[i];
        }
        return;
    }

    // ----- MFMA projection role: h = x @ W^T (bf16), s_i/s_j (fp32)
    const int mid = bx - bx / 3;
    if (mid >= mb) return;

    ushort* Bs = (ushort*)smem;   // 32 KB

    for (int i = tid; i < 2048; i += 256)
        ((float4*)Bs)[i] = ((const float4*)wfrag)[i];
    __syncthreads();

    const int lane = tid & 63;
    const int wv   = tid >> 6;
    const int m    = lane & 15;
    const int quad = lane >> 4;

    const int base = mid * 64 + wv * 16;
    int row = base + m;
    if (row >= n_nodes) row = n_nodes - 1;   // clamped loads, masked stores

    f32x4 acc0 = {0.f, 0.f, 0.f, 0.f};
    f32x4 acc1 = {0.f, 0.f, 0.f, 0.f};
    f32x4 acc2 = {0.f, 0.f, 0.f, 0.f};
    f32x4 acc3 = {0.f, 0.f, 0.f, 0.f};

    const float* xrow = x + (size_t)row * IN_C + quad * 8;

    #pragma unroll
    for (int t = 0; t < 8; ++t) {
        const float4 xa = *(const float4*)(xrow + t * 32);
        const float4 xb = *(const float4*)(xrow + t * 32 + 4);
        union { s16x8 v; uint32_t u[4]; } af;
        af.u[0] = pack_bf2(xa.x, xa.y);
        af.u[1] = pack_bf2(xa.z, xa.w);
        af.u[2] = pack_bf2(xb.x, xb.y);
        af.u[3] = pack_bf2(xb.z, xb.w);

        const s16x8 b0 = *(const s16x8*)(Bs + ((t * 4 + 0) * 64 + lane) * 8);
        const s16x8 b1 = *(const s16x8*)(Bs + ((t * 4 + 1) * 64 + lane) * 8);
        const s16x8 b2 = *(const s16x8*)(Bs + ((t * 4 + 2) * 64 + lane) * 8);
        const s16x8 b3 = *(const s16x8*)(Bs + ((t * 4 + 3) * 64 + lane) * 8);

        acc0 = __builtin_amdgcn_mfma_f32_16x16x32_bf16(af.v, b0, acc0, 0, 0, 0);
        acc1 = __builtin_amdgcn_mfma_f32_16x16x32_bf16(af.v, b1, acc1, 0, 0, 0);
        acc2 = __builtin_amdgcn_mfma_f32_16x16x32_bf16(af.v, b2, acc2, 0, 0, 0);
        acc3 = __builtin_amdgcn_mfma_f32_16x16x32_bf16(af.v, b3, acc3, 0, 0, 0);
    }

    // epilogue: C/D layout col = lane&15, row = quad*4 + reg
    const int c0 = lane & 15;
    const float ai0 = a[c0],      ai1 = a[c0 + 16], ai2 = a[c0 + 32], ai3 = a[c0 + 48];
    const float aj0 = a[64 + c0], aj1 = a[80 + c0], aj2 = a[96 + c0], aj3 = a[112 + c0];

    #pragma unroll
    for (int r = 0; r < 4; ++r) {
        const int rowr = base + quad * 4 + r;
        float pi = acc0[r] * ai0 + acc1[r] * ai1 + acc2[r] * ai2 + acc3[r] * ai3;
        float pj = acc0[r] * aj0 + acc1[r] * aj1 + acc2[r] * aj2 + acc3[r] * aj3;
        pi += __shfl_xor(pi, 1, 64);  pj += __shfl_xor(pj, 1, 64);
        pi += __shfl_xor(pi, 2, 64);  pj += __shfl_xor(pj, 2, 64);
        pi += __shfl_xor(pi, 4, 64);  pj += __shfl_xor(pj, 4, 64);
        pi += __shfl_xor(pi, 8, 64);  pj += __shfl_xor(pj, 8, 64);
        if (rowr < n_nodes) {
            ushort* hr = hb + (size_t)rowr * OUT_C + c0;
            hr[0]  = f2bf(acc0[r]);
            hr[16] = f2bf(acc1[r]);
            hr[32] = f2bf(acc2[r]);
            hr[48] = f2bf(acc3[r]);
            if (c0 == 0) { s_i[rowr] = pi; s_j[rowr] = pj; }
        }
    }
}

// ---------------------------------------------------------------------------
// Fused sort+gather: one 1024-thread block per 256-node bucket.
// (unchanged from the 280 µs measured version)
// ---------------------------------------------------------------------------
__global__ __launch_bounds__(1024) void sortgather_kernel(
    const uint32_t* __restrict__ rec, const ushort* __restrict__ hb,
    const float* __restrict__ s_i, const float* __restrict__ s_j,
    const int* __restrict__ cursor, float* __restrict__ out, int n_nodes)
{
    __shared__ uint32_t srt[CAP];        // 38 KB sorted records
    __shared__ int hcnt[BKT2];           // 1 KB
    __shared__ int nstart[BKT2 + 1];     // 1 KB
    __shared__ int lcur[BKT2];           // 1 KB
    __shared__ int sscan[BKT2];          // 1 KB

    const int b     = blockIdx.x;
    const int tid   = threadIdx.x;
    const int start = b * CAP;
    const int cnt   = min(cursor[b] - start, CAP);

    if (tid < BKT2) hcnt[tid] = 0;
    __syncthreads();

    // phase 1: histogram (vectorized global read; rec is L2-resident)
    const int cnt4 = cnt >> 2;
    for (int i = tid; i < cnt4; i += 1024) {
        const uint4 rv4 = ((const uint4*)(rec + start))[i];
        atomicAdd(&hcnt[rv4.x & (BKT2 - 1)], 1);
        atomicAdd(&hcnt[rv4.y & (BKT2 - 1)], 1);
        atomicAdd(&hcnt[rv4.z & (BKT2 - 1)], 1);
        atomicAdd(&hcnt[rv4.w & (BKT2 - 1)], 1);
    }
    for (int i = (cnt & ~3) + tid; i < cnt; i += 1024)
        atomicAdd(&hcnt[rec[start + i] & (BKT2 - 1)], 1);
    __syncthreads();

    // phase 2: inclusive scan over 256 node counts
    if (tid < BKT2) sscan[tid] = hcnt[tid];
    __syncthreads();
    for (int off = 1; off < BKT2; off <<= 1) {
        int mine = 0, other = 0;
        if (tid < BKT2) {
            mine  = sscan[tid];
            other = (tid >= off) ? sscan[tid - off] : 0;
        }
        __syncthreads();
        if (tid < BKT2) sscan[tid] = mine + other;
        __syncthreads();
    }
    if (tid < BKT2) {
        const int excl = sscan[tid] - hcnt[tid];
        nstart[tid] = excl;
        lcur[tid]   = excl;
    }
    if (tid == 0) nstart[BKT2] = cnt;
    __syncthreads();

    // phase 3: scatter into per-node CSR order inside LDS
    for (int i = tid; i < cnt; i += 1024) {
        const uint32_t rv = rec[start + i];
        srt[atomicAdd(&lcur[rv & (BKT2 - 1)], 1)] = rv;
    }
    __syncthreads();

    // phase 4: per-node gather (16 nodes per wave, records from LDS)
    const int lane = tid & 63;
    const int wv   = tid >> 6;
    const int g    = lane >> 3;          // edge slot 0..7
    const int l8   = lane & 7;           // channel block
    const uint32_t loff = (uint32_t)(l8 << 4);
    const char* hbB = (const char*)hb;

    for (int k = 0; k < BKT2 / 16; ++k) {
        const int nl   = wv * (BKT2 / 16) + k;
        const int node = b * BKT2 + nl;
        if (node >= n_nodes) break;
        const int o  = nstart[nl];
        const int oe = nstart[nl + 1];
        const float si = s_i[node];

        f32x2 a01 = {0.f, 0.f}, a23 = {0.f, 0.f};
        f32x2 a45 = {0.f, 0.f}, a67 = {0.f, 0.f};
        float dsum = 0.f;

        int e = o;
        for (; e + 32 <= oe; e += 32) {
            uint32_t rv[4];
            #pragma unroll
            for (int q = 0; q < 4; ++q) rv[q] = srt[e + q * 8 + g];
            float sj[4]; uint32_t off[4];
            #pragma unroll
            for (int q = 0; q < 4; ++q) {
                sj[q]  = s_j[rv[q] >> 8];
                off[q] = ((rv[q] & 0xFFFFFF00u) >> 1) + loff;   // r*128 + l8*16
            }
            uint4 hv[4];
            #pragma unroll
            for (int q = 0; q < 4; ++q) hv[q] = *(const uint4*)(hbB + off[q]);
            #pragma unroll
            for (int q = 0; q < 4; ++q) {
                const float t  = si + sj[q];
                const float ex = __expf(fmaxf(t, NEG_SLOPE * t));
                const f32x2 e2 = {ex, ex};
                f32x2 h;
                h[0] = __uint_as_float(hv[q].x << 16);
                h[1] = __uint_as_float(hv[q].x & 0xffff0000u);
                a01 += e2 * h;
                h[0] = __uint_as_float(hv[q].y << 16);
                h[1] = __uint_as_float(hv[q].y & 0xffff0000u);
                a23 += e2 * h;
                h[0] = __uint_as_float(hv[q].z << 16);
                h[1] = __uint_as_float(hv[q].z & 0xffff0000u);
                a45 += e2 * h;
                h[0] = __uint_as_float(hv[q].w << 16);
                h[1] = __uint_as_float(hv[q].w & 0xffff0000u);
                a67 += e2 * h;
                dsum += ex;
            }
        }
        for (; e + 8 <= oe; e += 8) {
            const uint32_t rv = srt[e + g];
            const float sjv = s_j[rv >> 8];
            const uint32_t off = ((rv & 0xFFFFFF00u) >> 1) + loff;
            const uint4 hv = *(const uint4*)(hbB + off);
            const float t  = si + sjv;
            const float ex = __expf(fmaxf(t, NEG_SLOPE * t));
            const f32x2 e2 = {ex, ex};
            f32x2 h;
            h[0] = __uint_as_float(hv.x << 16);
            h[1] = __uint_as_float(hv.x & 0xffff0000u);
            a01 += e2 * h;
            h[0] = __uint_as_float(hv.y << 16);
            h[1] = __uint_as_float(hv.y & 0xffff0000u);
            a23 += e2 * h;
            h[0] = __uint_as_float(hv.z << 16);
            h[1] = __uint_as_float(hv.z & 0xffff0000u);
            a45 += e2 * h;
            h[0] = __uint_as_float(hv.w << 16);
            h[1] = __uint_as_float(hv.w & 0xffff0000u);
            a67 += e2 * h;
            dsum += ex;
        }
        if (e < oe) {
            const int m = oe - e;                    // 1..7
            const uint32_t rv = srt[e + (g < m ? g : m - 1)];
            const float sjv = s_j[rv >> 8];
            const uint32_t off = ((rv & 0xFFFFFF00u) >> 1) + loff;
            const uint4 hv = *(const uint4*)(hbB + off);
            const float t  = si + sjv;
            const float ex = (g < m) ? __expf(fmaxf(t, NEG_SLOPE * t)) : 0.f;
            const f32x2 e2 = {ex, ex};
            f32x2 h;
            h[0] = __uint_as_float(hv.x << 16);
            h[1] = __uint_as_float(hv.x & 0xffff0000u);
            a01 += e2 * h;
            h[0] = __uint_as_float(hv.y << 16);
            h[1] = __uint_as_float(hv.y & 0xffff0000u);
            a23 += e2 * h;
            h[0] = __uint_as_float(hv.z << 16);
            h[1] = __uint_as_float(hv.z & 0xffff0000u);
            a45 += e2 * h;
            h[0] = __uint_as_float(hv.w << 16);
            h[1] = __uint_as_float(hv.w & 0xffff0000u);
            a67 += e2 * h;
            dsum += ex;
        }

        // cross-group reduction over the 8 edge slots (l8 preserved)
        #pragma unroll
        for (int s = 8; s <= 32; s <<= 1) {
            a01[0] += __shfl_xor(a01[0], s, 64);
            a01[1] += __shfl_xor(a01[1], s, 64);
            a23[0] += __shfl_xor(a23[0], s, 64);
            a23[1] += __shfl_xor(a23[1], s, 64);
            a45[0] += __shfl_xor(a45[0], s, 64);
            a45[1] += __shfl_xor(a45[1], s, 64);
            a67[0] += __shfl_xor(a67[0], s, 64);
            a67[1] += __shfl_xor(a67[1], s, 64);
            dsum   += __shfl_xor(dsum,   s, 64);
        }

        // self loop: row = col = node
        const float t0  = si + s_j[node];
        const float ex0 = __expf(fmaxf(t0, NEG_SLOPE * t0));
        const uint4 hs = *(const uint4*)(hbB + (size_t)node * 128 + loff);
        a01[0] += ex0 * __uint_as_float(hs.x << 16);
        a01[1] += ex0 * __uint_as_float(hs.x & 0xffff0000u);
        a23[0] += ex0 * __uint_as_float(hs.y << 16);
        a23[1] += ex0 * __uint_as_float(hs.y & 0xffff0000u);
        a45[0] += ex0 * __uint_as_float(hs.z << 16);
        a45[1] += ex0 * __uint_as_float(hs.z & 0xffff0000u);
        a67[0] += ex0 * __uint_as_float(hs.w << 16);
        a67[1] += ex0 * __uint_as_float(hs.w & 0xffff0000u);
        dsum += ex0;

        if (g == 0) {
            const float inv = 1.0f / dsum;
            f32x4 o4;
            o4[0] = a01[0] * inv;
            o4[1] = a01[1] * inv;
            o4[2] = a23[0] * inv;
            o4[3] = a23[1] * inv;
            float* op = out + (size_t)node * OUT_C + (l8 << 3);
            __builtin_nontemporal_store(o4, (f32x4*)op);
            o4[0] = a45[0] * inv;
            o4[1] = a45[1] * inv;
            o4[2] = a67[0] * inv;
            o4[3] = a67[1] * inv;
            __builtin_nontemporal_store(o4, (f32x4*)(op + 4));
        }
    }
}

extern "C" void kernel_launch(void* const* d_in, const int* in_sizes, int n_in,
                              void* d_out, int out_size, void* d_ws, size_t ws_size,
                              hipStream_t stream)
{
    const float* x  = (const float*)d_in[0];
    const int*   ei = (const int*)d_in[1];
    const float* W  = (const float*)d_in[2];
    const float* a  = (const float*)d_in[3];

    const int N  = in_sizes[0] / IN_C;     // 100000
    const int E  = in_sizes[1] / 2;        // 3200000
    const int NB = (N + BKT2 - 1) / BKT2;  // 391

    float* out = (float*)d_out;

    // workspace carve-up (~29 MB)
    char* ws = (char*)d_ws;
    ushort* hb      = (ushort*)ws;                ws += (size_t)N * OUT_C * 2;  // 12.8 MB
    float*  s_i     = (float*)ws;                 ws += (size_t)N * 4;
    float*  s_j     = (float*)ws;                 ws += (size_t)N * 4;
    int*    cursor  = (int*)ws;                   ws += (size_t)MAXB * 4;
    ws = (char*)(((uintptr_t)ws + 15) & ~(uintptr_t)15);
    ushort* wfrag   = (ushort*)ws;                ws += 32 * 64 * 8 * 2;        // 32 KB
    ws = (char*)(((uintptr_t)ws + 15) & ~(uintptr_t)15);
    uint32_t* rec   = (uint32_t*)ws;              // NB * CAP * 4 B = 15.2 MB

    // 1. W fragment conversion + cursor init
    hipLaunchKernelGGL(wconv_kernel, dim3(65), dim3(256), 0, stream,
                       W, wfrag, cursor, NB);

    // 2. merged projection (MFMA) + partition — interleaved 1:2 for overlap
    const int PB = (E + PCHUNK - 1) / PCHUNK;   // 782 partition blocks
    const int MB = (N + 63) / 64;               // 1563 mfma blocks
    hipLaunchKernelGGL(fused_proj_part, dim3(3 * PB), dim3(256), 0, stream,
                       x, wfrag, a, hb, s_i, s_j, N,
                       ei, cursor, rec, E, NB, MB);

    // 3. fused per-bucket LDS sort + gather-aggregate
    hipLaunchKernelGGL(sortgather_kernel, dim3(NB), dim3(1024), 0, stream,
                       rec, hb, s_i, s_j, cursor, out, N);
}

// Round 15
// 269.682 us; speedup vs baseline: 1.0661x; 1.0385x over previous
//
#include <hip/hip_runtime.h>
#include <hip/hip_bf16.h>
#include <cstddef>
#include <cstdint>

#define IN_C 256
#define OUT_C 64
#define NEG_SLOPE 0.2f
#define BKT2 256       // nodes per destination bucket (bucket = c >> 8)
#define PCHUNK 4096    // edges per block in partition role
#define MAXB 512       // bucket-slot array size (>= number of buckets = 391)
#define CAP 9728       // fixed record capacity per bucket (mean 8163, +17 sigma)

typedef __attribute__((ext_vector_type(4))) float f32x4;
typedef __attribute__((ext_vector_type(2))) float f32x2;
typedef __attribute__((ext_vector_type(8))) short s16x8;

__device__ __forceinline__ ushort f2bf(float f)
{
    uint32_t u = __float_as_uint(f);
    u += 0x7fffu + ((u >> 16) & 1u);   // round-to-nearest-even
    return (ushort)(u >> 16);
}

// pack two fp32 -> {bf16(f1)<<16 | bf16(f0)}
__device__ __forceinline__ uint32_t pack_bf2(float f0, float f1)
{
    const uint32_t u0 = __float_as_uint(f0) + 0x8000u;
    const uint32_t u1 = __float_as_uint(f1) + 0x8000u;
    return (u1 & 0xffff0000u) | (u0 >> 16);
}

// ---------------------------------------------------------------------------
// W -> bf16 B-fragment order (blocks 0..63); block 64 inits bucket cursors.
// ---------------------------------------------------------------------------
__global__ __launch_bounds__(256) void wconv_kernel(
    const float* __restrict__ W, ushort* __restrict__ wfrag,
    int* __restrict__ cursor, int nb)
{
    if (blockIdx.x == 64) {
        for (int i = threadIdx.x; i < nb; i += 256) cursor[i] = i * CAP;
        return;
    }
    const int idx = blockIdx.x * 256 + threadIdx.x;
    const int j = idx & 7;
    const int l = (idx >> 3) & 63;
    const int n = (idx >> 9) & 3;
    const int t = idx >> 11;
    const int k   = t * 32 + ((l >> 4) << 3) + j;
    const int col = n * 16 + (l & 15);
    wfrag[idx] = f2bf(W[col * IN_C + k]);
}

// ---------------------------------------------------------------------------
// Merged kernel, INTERLEAVED roles: bx%3==2 -> partition (pid=bx/3, exactly
// PB blocks), else MFMA projection (mid=bx-bx/3, guard >= mb).  1:2 mix per
// CU so partition's latency stalls are filled by mfma's VALU/MFMA waves.
// LDS exactly 32 KB -> 5 blocks/CU.
// MFMA role: all 16 x-row float4 loads issued UP FRONT (xs[16] staging,
// static indices -> registers) and BEFORE the Bs copy + barrier, so the
// 16 independent global loads are in flight under the LDS staging.
// Round-14 counters (VGPR=48, VALUBusy 7%) showed the compiler was issuing
// x loads just-in-time ~2-deep; this forces 16-deep MLP per wave.
// ---------------------------------------------------------------------------
__global__ __launch_bounds__(256) void fused_proj_part(
    const float* __restrict__ x, const ushort* __restrict__ wfrag,
    const float* __restrict__ a, ushort* __restrict__ hb,
    float* __restrict__ s_i, float* __restrict__ s_j, int n_nodes,
    const int* __restrict__ ei, int* __restrict__ cursor,
    uint32_t* __restrict__ rec, int n_edges, int nb, int mb)
{
    __shared__ __align__(16) char smem[32 * 1024];

    const int tid = threadIdx.x;
    const int bx  = (int)blockIdx.x;

    if (bx % 3 == 2) {
        // ----- partition role: 4096 edges, LDS counting-sort, coalesced flush
        const int pid = bx / 3;
        int* hist  = (int*)smem;                     // 2 KB (512 slots)
        int* lbase = (int*)(smem + 2048);            // 2 KB
        int* gbase = (int*)(smem + 4096);            // 2 KB
        int* lcur  = (int*)(smem + 6144);            // 2 KB
        uint32_t* srt  = (uint32_t*)(smem + 8192);   // 16 KB
        uint16_t* bmap = (uint16_t*)(smem + 24576);  // 8 KB
        int* wtot = (int*)(smem + 8192);             // aliases srt[0..3]:
        // written before barrier-1, read right after; srt first written
        // only after barrier-2 -> no overlap.

        const int base = pid * PCHUNK;
        const int lim  = min(PCHUNK, n_edges - base);

        hist[tid] = 0;
        hist[tid + 256] = 0;
        __syncthreads();

        int rA[PCHUNK / 256], cA[PCHUNK / 256];
        #pragma unroll
        for (int k = 0; k < PCHUNK / 256; ++k) {
            const int i = tid + (k << 8);
            if (i < lim) {
                rA[k] = __builtin_nontemporal_load(ei + base + i);
                cA[k] = __builtin_nontemporal_load(ei + n_edges + base + i);
                atomicAdd(&hist[(uint32_t)cA[k] >> 8], 1);
            }
        }
        __syncthreads();

        // scan 512 slots with 256 threads: thread t owns slots 2t, 2t+1.
        const int h0 = hist[2 * tid];
        const int h1 = hist[2 * tid + 1];
        const int pv = h0 + h1;
        const int lane = tid & 63;
        const int w    = tid >> 6;
        int incl = pv;
        #pragma unroll
        for (int d = 1; d < 64; d <<= 1) {
            const int o = __shfl_up(incl, d, 64);
            if (lane >= d) incl += o;
        }
        if (lane == 63) wtot[w] = incl;
        __syncthreads();
        int wpre = 0;
        for (int q = 0; q < w; ++q) wpre += wtot[q];
        const int excl_pair = incl + wpre - pv;   // exclusive prefix of pair tid

        lbase[2 * tid]     = excl_pair;
        lbase[2 * tid + 1] = excl_pair + h0;
        lcur[2 * tid]      = excl_pair;
        lcur[2 * tid + 1]  = excl_pair + h0;
        gbase[2 * tid]     = (2 * tid < nb && h0 > 0)
                             ? atomicAdd(&cursor[2 * tid], h0) : 0;
        gbase[2 * tid + 1] = (2 * tid + 1 < nb && h1 > 0)
                             ? atomicAdd(&cursor[2 * tid + 1], h1) : 0;
        __syncthreads();

        // scatter into LDS staging in block-sorted order
        #pragma unroll
        for (int k = 0; k < PCHUNK / 256; ++k) {
            const int i = tid + (k << 8);
            if (i < lim) {
                const int r = rA[k];
                const int c = cA[k];
                const int b = (uint32_t)c >> 8;
                const int pos = atomicAdd(&lcur[b], 1);
                srt[pos]  = ((uint32_t)r << 8) | (uint32_t)(c & (BKT2 - 1));
                bmap[pos] = (uint16_t)b;
            }
        }
        __syncthreads();

        // linear flush: piecewise-contiguous coalesced burst
        for (int i = tid; i < lim; i += 256) {
            const int b = bmap[i];
            rec[gbase[b] + (i - lbase[b])] = srt[i];
        }
        return;
    }

    // ----- MFMA projection role: h = x @ W^T (bf16), s_i/s_j (fp32)
    const int mid = bx - bx / 3;
    if (mid >= mb) return;

    ushort* Bs = (ushort*)smem;   // 32 KB

    const int lane = tid & 63;
    const int wv   = tid >> 6;
    const int m    = lane & 15;
    const int quad = lane >> 4;

    const int base = mid * 64 + wv * 16;
    int row = base + m;
    if (row >= n_nodes) row = n_nodes - 1;   // clamped loads, masked stores

    const float* xrow = x + (size_t)row * IN_C + quad * 8;

    // issue ALL 16 x loads first — 16-deep MLP, latency hides under Bs copy
    float4 xs[16];
    #pragma unroll
    for (int t = 0; t < 8; ++t) {
        xs[2 * t]     = *(const float4*)(xrow + t * 32);
        xs[2 * t + 1] = *(const float4*)(xrow + t * 32 + 4);
    }

    for (int i = tid; i < 2048; i += 256)
        ((float4*)Bs)[i] = ((const float4*)wfrag)[i];
    __syncthreads();

    f32x4 acc0 = {0.f, 0.f, 0.f, 0.f};
    f32x4 acc1 = {0.f, 0.f, 0.f, 0.f};
    f32x4 acc2 = {0.f, 0.f, 0.f, 0.f};
    f32x4 acc3 = {0.f, 0.f, 0.f, 0.f};

    #pragma unroll
    for (int t = 0; t < 8; ++t) {
        const float4 xa = xs[2 * t];
        const float4 xb = xs[2 * t + 1];
        union { s16x8 v; uint32_t u[4]; } af;
        af.u[0] = pack_bf2(xa.x, xa.y);
        af.u[1] = pack_bf2(xa.z, xa.w);
        af.u[2] = pack_bf2(xb.x, xb.y);
        af.u[3] = pack_bf2(xb.z, xb.w);

        const s16x8 b0 = *(const s16x8*)(Bs + ((t * 4 + 0) * 64 + lane) * 8);
        const s16x8 b1 = *(const s16x8*)(Bs + ((t * 4 + 1) * 64 + lane) * 8);
        const s16x8 b2 = *(const s16x8*)(Bs + ((t * 4 + 2) * 64 + lane) * 8);
        const s16x8 b3 = *(const s16x8*)(Bs + ((t * 4 + 3) * 64 + lane) * 8);

        acc0 = __builtin_amdgcn_mfma_f32_16x16x32_bf16(af.v, b0, acc0, 0, 0, 0);
        acc1 = __builtin_amdgcn_mfma_f32_16x16x32_bf16(af.v, b1, acc1, 0, 0, 0);
        acc2 = __builtin_amdgcn_mfma_f32_16x16x32_bf16(af.v, b2, acc2, 0, 0, 0);
        acc3 = __builtin_amdgcn_mfma_f32_16x16x32_bf16(af.v, b3, acc3, 0, 0, 0);
    }

    // epilogue: C/D layout col = lane&15, row = quad*4 + reg
    const int c0 = lane & 15;
    const float ai0 = a[c0],      ai1 = a[c0 + 16], ai2 = a[c0 + 32], ai3 = a[c0 + 48];
    const float aj0 = a[64 + c0], aj1 = a[80 + c0], aj2 = a[96 + c0], aj3 = a[112 + c0];

    #pragma unroll
    for (int r = 0; r < 4; ++r) {
        const int rowr = base + quad * 4 + r;
        float pi = acc0[r] * ai0 + acc1[r] * ai1 + acc2[r] * ai2 + acc3[r] * ai3;
        float pj = acc0[r] * aj0 + acc1[r] * aj1 + acc2[r] * aj2 + acc3[r] * aj3;
        pi += __shfl_xor(pi, 1, 64);  pj += __shfl_xor(pj, 1, 64);
        pi += __shfl_xor(pi, 2, 64);  pj += __shfl_xor(pj, 2, 64);
        pi += __shfl_xor(pi, 4, 64);  pj += __shfl_xor(pj, 4, 64);
        pi += __shfl_xor(pi, 8, 64);  pj += __shfl_xor(pj, 8, 64);
        if (rowr < n_nodes) {
            ushort* hr = hb + (size_t)rowr * OUT_C + c0;
            hr[0]  = f2bf(acc0[r]);
            hr[16] = f2bf(acc1[r]);
            hr[32] = f2bf(acc2[r]);
            hr[48] = f2bf(acc3[r]);
            if (c0 == 0) { s_i[rowr] = pi; s_j[rowr] = pj; }
        }
    }
}

// ---------------------------------------------------------------------------
// Fused sort+gather: one 1024-thread block per 256-node bucket.
// (unchanged from the 280 µs measured version)
// ---------------------------------------------------------------------------
__global__ __launch_bounds__(1024) void sortgather_kernel(
    const uint32_t* __restrict__ rec, const ushort* __restrict__ hb,
    const float* __restrict__ s_i, const float* __restrict__ s_j,
    const int* __restrict__ cursor, float* __restrict__ out, int n_nodes)
{
    __shared__ uint32_t srt[CAP];        // 38 KB sorted records
    __shared__ int hcnt[BKT2];           // 1 KB
    __shared__ int nstart[BKT2 + 1];     // 1 KB
    __shared__ int lcur[BKT2];           // 1 KB
    __shared__ int sscan[BKT2];          // 1 KB

    const int b     = blockIdx.x;
    const int tid   = threadIdx.x;
    const int start = b * CAP;
    const int cnt   = min(cursor[b] - start, CAP);

    if (tid < BKT2) hcnt[tid] = 0;
    __syncthreads();

    // phase 1: histogram (vectorized global read; rec is L2-resident)
    const int cnt4 = cnt >> 2;
    for (int i = tid; i < cnt4; i += 1024) {
        const uint4 rv4 = ((const uint4*)(rec + start))[i];
        atomicAdd(&hcnt[rv4.x & (BKT2 - 1)], 1);
        atomicAdd(&hcnt[rv4.y & (BKT2 - 1)], 1);
        atomicAdd(&hcnt[rv4.z & (BKT2 - 1)], 1);
        atomicAdd(&hcnt[rv4.w & (BKT2 - 1)], 1);
    }
    for (int i = (cnt & ~3) + tid; i < cnt; i += 1024)
        atomicAdd(&hcnt[rec[start + i] & (BKT2 - 1)], 1);
    __syncthreads();

    // phase 2: inclusive scan over 256 node counts
    if (tid < BKT2) sscan[tid] = hcnt[tid];
    __syncthreads();
    for (int off = 1; off < BKT2; off <<= 1) {
        int mine = 0, other = 0;
        if (tid < BKT2) {
            mine  = sscan[tid];
            other = (tid >= off) ? sscan[tid - off] : 0;
        }
        __syncthreads();
        if (tid < BKT2) sscan[tid] = mine + other;
        __syncthreads();
    }
    if (tid < BKT2) {
        const int excl = sscan[tid] - hcnt[tid];
        nstart[tid] = excl;
        lcur[tid]   = excl;
    }
    if (tid == 0) nstart[BKT2] = cnt;
    __syncthreads();

    // phase 3: scatter into per-node CSR order inside LDS
    for (int i = tid; i < cnt; i += 1024) {
        const uint32_t rv = rec[start + i];
        srt[atomicAdd(&lcur[rv & (BKT2 - 1)], 1)] = rv;
    }
    __syncthreads();

    // phase 4: per-node gather (16 nodes per wave, records from LDS)
    const int lane = tid & 63;
    const int wv   = tid >> 6;
    const int g    = lane >> 3;          // edge slot 0..7
    const int l8   = lane & 7;           // channel block
    const uint32_t loff = (uint32_t)(l8 << 4);
    const char* hbB = (const char*)hb;

    for (int k = 0; k < BKT2 / 16; ++k) {
        const int nl   = wv * (BKT2 / 16) + k;
        const int node = b * BKT2 + nl;
        if (node >= n_nodes) break;
        const int o  = nstart[nl];
        const int oe = nstart[nl + 1];
        const float si = s_i[node];

        f32x2 a01 = {0.f, 0.f}, a23 = {0.f, 0.f};
        f32x2 a45 = {0.f, 0.f}, a67 = {0.f, 0.f};
        float dsum = 0.f;

        int e = o;
        for (; e + 32 <= oe; e += 32) {
            uint32_t rv[4];
            #pragma unroll
            for (int q = 0; q < 4; ++q) rv[q] = srt[e + q * 8 + g];
            float sj[4]; uint32_t off[4];
            #pragma unroll
            for (int q = 0; q < 4; ++q) {
                sj[q]  = s_j[rv[q] >> 8];
                off[q] = ((rv[q] & 0xFFFFFF00u) >> 1) + loff;   // r*128 + l8*16
            }
            uint4 hv[4];
            #pragma unroll
            for (int q = 0; q < 4; ++q) hv[q] = *(const uint4*)(hbB + off[q]);
            #pragma unroll
            for (int q = 0; q < 4; ++q) {
                const float t  = si + sj[q];
                const float ex = __expf(fmaxf(t, NEG_SLOPE * t));
                const f32x2 e2 = {ex, ex};
                f32x2 h;
                h[0] = __uint_as_float(hv[q].x << 16);
                h[1] = __uint_as_float(hv[q].x & 0xffff0000u);
                a01 += e2 * h;
                h[0] = __uint_as_float(hv[q].y << 16);
                h[1] = __uint_as_float(hv[q].y & 0xffff0000u);
                a23 += e2 * h;
                h[0] = __uint_as_float(hv[q].z << 16);
                h[1] = __uint_as_float(hv[q].z & 0xffff0000u);
                a45 += e2 * h;
                h[0] = __uint_as_float(hv[q].w << 16);
                h[1] = __uint_as_float(hv[q].w & 0xffff0000u);
                a67 += e2 * h;
                dsum += ex;
            }
        }
        for (; e + 8 <= oe; e += 8) {
            const uint32_t rv = srt[e + g];
            const float sjv = s_j[rv >> 8];
            const uint32_t off = ((rv & 0xFFFFFF00u) >> 1) + loff;
            const uint4 hv = *(const uint4*)(hbB + off);
            const float t  = si + sjv;
            const float ex = __expf(fmaxf(t, NEG_SLOPE * t));
            const f32x2 e2 = {ex, ex};
            f32x2 h;
            h[0] = __uint_as_float(hv.x << 16);
            h[1] = __uint_as_float(hv.x & 0xffff0000u);
            a01 += e2 * h;
            h[0] = __uint_as_float(hv.y << 16);
            h[1] = __uint_as_float(hv.y & 0xffff0000u);
            a23 += e2 * h;
            h[0] = __uint_as_float(hv.z << 16);
            h[1] = __uint_as_float(hv.z & 0xffff0000u);
            a45 += e2 * h;
            h[0] = __uint_as_float(hv.w << 16);
            h[1] = __uint_as_float(hv.w & 0xffff0000u);
            a67 += e2 * h;
            dsum += ex;
        }
        if (e < oe) {
            const int m = oe - e;                    // 1..7
            const uint32_t rv = srt[e + (g < m ? g : m - 1)];
            const float sjv = s_j[rv >> 8];
            const uint32_t off = ((rv & 0xFFFFFF00u) >> 1) + loff;
            const uint4 hv = *(const uint4*)(hbB + off);
            const float t  = si + sjv;
            const float ex = (g < m) ? __expf(fmaxf(t, NEG_SLOPE * t)) : 0.f;
            const f32x2 e2 = {ex, ex};
            f32x2 h;
            h[0] = __uint_as_float(hv.x << 16);
            h[1] = __uint_as_float(hv.x & 0xffff0000u);
            a01 += e2 * h;
            h[0] = __uint_as_float(hv.y << 16);
            h[1] = __uint_as_float(hv.y & 0xffff0000u);
            a23 += e2 * h;
            h[0] = __uint_as_float(hv.z << 16);
            h[1] = __uint_as_float(hv.z & 0xffff0000u);
            a45 += e2 * h;
            h[0] = __uint_as_float(hv.w << 16);
            h[1] = __uint_as_float(hv.w & 0xffff0000u);
            a67 += e2 * h;
            dsum += ex;
        }

        // cross-group reduction over the 8 edge slots (l8 preserved)
        #pragma unroll
        for (int s = 8; s <= 32; s <<= 1) {
            a01[0] += __shfl_xor(a01[0], s, 64);
            a01[1] += __shfl_xor(a01[1], s, 64);
            a23[0] += __shfl_xor(a23[0], s, 64);
            a23[1] += __shfl_xor(a23[1], s, 64);
            a45[0] += __shfl_xor(a45[0], s, 64);
            a45[1] += __shfl_xor(a45[1], s, 64);
            a67[0] += __shfl_xor(a67[0], s, 64);
            a67[1] += __shfl_xor(a67[1], s, 64);
            dsum   += __shfl_xor(dsum,   s, 64);
        }

        // self loop: row = col = node
        const float t0  = si + s_j[node];
        const float ex0 = __expf(fmaxf(t0, NEG_SLOPE * t0));
        const uint4 hs = *(const uint4*)(hbB + (size_t)node * 128 + loff);
        a01[0] += ex0 * __uint_as_float(hs.x << 16);
        a01[1] += ex0 * __uint_as_float(hs.x & 0xffff0000u);
        a23[0] += ex0 * __uint_as_float(hs.y << 16);
        a23[1] += ex0 * __uint_as_float(hs.y & 0xffff0000u);
        a45[0] += ex0 * __uint_as_float(hs.z << 16);
        a45[1] += ex0 * __uint_as_float(hs.z & 0xffff0000u);
        a67[0] += ex0 * __uint_as_float(hs.w << 16);
        a67[1] += ex0 * __uint_as_float(hs.w & 0xffff0000u);
        dsum += ex0;

        if (g == 0) {
            const float inv = 1.0f / dsum;
            f32x4 o4;
            o4[0] = a01[0] * inv;
            o4[1] = a01[1] * inv;
            o4[2] = a23[0] * inv;
            o4[3] = a23[1] * inv;
            float* op = out + (size_t)node * OUT_C + (l8 << 3);
            __builtin_nontemporal_store(o4, (f32x4*)op);
            o4[0] = a45[0] * inv;
            o4[1] = a45[1] * inv;
            o4[2] = a67[0] * inv;
            o4[3] = a67[1] * inv;
            __builtin_nontemporal_store(o4, (f32x4*)(op + 4));
        }
    }
}

extern "C" void kernel_launch(void* const* d_in, const int* in_sizes, int n_in,
                              void* d_out, int out_size, void* d_ws, size_t ws_size,
                              hipStream_t stream)
{
    const float* x  = (const float*)d_in[0];
    const int*   ei = (const int*)d_in[1];
    const float* W  = (const float*)d_in[2];
    const float* a  = (const float*)d_in[3];

    const int N  = in_sizes[0] / IN_C;     // 100000
    const int E  = in_sizes[1] / 2;        // 3200000
    const int NB = (N + BKT2 - 1) / BKT2;  // 391

    float* out = (float*)d_out;

    // workspace carve-up (~29 MB)
    char* ws = (char*)d_ws;
    ushort* hb      = (ushort*)ws;                ws += (size_t)N * OUT_C * 2;  // 12.8 MB
    float*  s_i     = (float*)ws;                 ws += (size_t)N * 4;
    float*  s_j     = (float*)ws;                 ws += (size_t)N * 4;
    int*    cursor  = (int*)ws;                   ws += (size_t)MAXB * 4;
    ws = (char*)(((uintptr_t)ws + 15) & ~(uintptr_t)15);
    ushort* wfrag   = (ushort*)ws;                ws += 32 * 64 * 8 * 2;        // 32 KB
    ws = (char*)(((uintptr_t)ws + 15) & ~(uintptr_t)15);
    uint32_t* rec   = (uint32_t*)ws;              // NB * CAP * 4 B = 15.2 MB

    // 1. W fragment conversion + cursor init
    hipLaunchKernelGGL(wconv_kernel, dim3(65), dim3(256), 0, stream,
                       W, wfrag, cursor, NB);

    // 2. merged projection (MFMA) + partition — interleaved 1:2 for overlap
    const int PB = (E + PCHUNK - 1) / PCHUNK;   // 782 partition blocks
    const int MB = (N + 63) / 64;               // 1563 mfma blocks
    hipLaunchKernelGGL(fused_proj_part, dim3(3 * PB), dim3(256), 0, stream,
                       x, wfrag, a, hb, s_i, s_j, N,
                       ei, cursor, rec, E, NB, MB);

    // 3. fused per-bucket LDS sort + gather-aggregate
    hipLaunchKernelGGL(sortgather_kernel, dim3(NB), dim3(1024), 0, stream,
                       rec, hb, s_i, s_j, cursor, out, N);
}